// Round 1
// baseline (426.039 us; speedup 1.0000x reference)
//
#include <hip/hip_runtime.h>
#include <math.h>

// TemporalEncoder: out[t, b, d] = (t == floor(sigmoid(x[b,d]) * (T-1))) ? 1 : 0
// B=256, D=4096, T=100. Output 419 MB fp32 -> write-BW bound (~67 us floor
// at 6.3 TB/s). One thread per 4 input elements: compute spike times once,
// then stream T coalesced float4 stores (stride B*D per t-plane).

typedef __attribute__((ext_vector_type(4))) float f32x4;

__device__ __forceinline__ float sigmoidf(float x) {
    // Match f32 expit: 1/(1+exp(-x)). expf is the ~1-ulp ocml path.
    return 1.0f / (1.0f + expf(-x));
}

__global__ __launch_bounds__(256) void temporal_encoder_kernel(
    const float* __restrict__ x, float* __restrict__ out,
    int n /* = B*D */, int T) {
    const int tid = blockIdx.x * blockDim.x + threadIdx.x;
    const int e = tid * 4;
    if (e + 3 < n) {
        f32x4 v = *reinterpret_cast<const f32x4*>(x + e);
        const float tm1 = (float)(T - 1);
        // floor == trunc since sigmoid >= 0
        const int st0 = (int)(sigmoidf(v.x) * tm1);
        const int st1 = (int)(sigmoidf(v.y) * tm1);
        const int st2 = (int)(sigmoidf(v.z) * tm1);
        const int st3 = (int)(sigmoidf(v.w) * tm1);
        float* p = out + e;
        for (int t = 0; t < T; ++t) {
            f32x4 o;
            o.x = (t == st0) ? 1.0f : 0.0f;
            o.y = (t == st1) ? 1.0f : 0.0f;
            o.z = (t == st2) ? 1.0f : 0.0f;
            o.w = (t == st3) ? 1.0f : 0.0f;
            *reinterpret_cast<f32x4*>(p) = o;
            p += n;
        }
    } else if (e < n) {
        // scalar tail (not hit for B*D = 1048576, kept for safety)
        const float tm1 = (float)(T - 1);
        for (int i = e; i < n; ++i) {
            const int st = (int)(sigmoidf(x[i]) * tm1);
            float* p = out + i;
            for (int t = 0; t < T; ++t) {
                *p = (t == st) ? 1.0f : 0.0f;
                p += n;
            }
        }
    }
}

extern "C" void kernel_launch(void* const* d_in, const int* in_sizes, int n_in,
                              void* d_out, int out_size, void* d_ws, size_t ws_size,
                              hipStream_t stream) {
    const float* x = (const float*)d_in[0];
    float* out = (float*)d_out;
    const int n = in_sizes[0];        // B*D = 1048576
    const int T = out_size / n;       // 100
    const int threads = 256;
    const int vec_elems = 4;
    const int nthreads_total = (n + vec_elems - 1) / vec_elems;
    const int blocks = (nthreads_total + threads - 1) / threads;
    temporal_encoder_kernel<<<blocks, threads, 0, stream>>>(x, out, n, T);
}

// Round 2
// 401.590 us; speedup vs baseline: 1.0609x; 1.0609x over previous
//
#include <hip/hip_runtime.h>
#include <math.h>

// TemporalEncoder: out[t, b, d] = (t == floor(sigmoid(x[b,d]) * (T-1))) ? 1 : 0
// B=256, D=4096, T=100. Output 419 MB fp32 -> pure write-BW bound.
//
// Round-1 lesson: one-thread-per-element looping over t gives scattered 1 KB
// bursts (4 MB plane stride) -> 1.0 TB/s. Harness fillBuffer hits 6.2 TB/s
// with a sequential stream. So: two passes.
//   Pass 1: spike times -> d_ws as uchar (1 MB, L2-resident afterwards).
//   Pass 2: output-major 2D grid; each block writes 4 KB contiguous, blocks
//           laid out sequentially -> fill-shaped write stream.

typedef __attribute__((ext_vector_type(4))) float f32x4;

__device__ __forceinline__ float sigmoidf(float x) {
    return 1.0f / (1.0f + expf(-x));  // matches f32 expit to 0 ulp vs np ref (R1)
}

__global__ __launch_bounds__(256) void spike_time_kernel(
    const float* __restrict__ x, unsigned char* __restrict__ st,
    int n, float tm1) {
    const int e = (blockIdx.x * 256 + threadIdx.x) * 4;
    if (e + 3 < n) {
        f32x4 v = *reinterpret_cast<const f32x4*>(x + e);
        uchar4 s;
        s.x = (unsigned char)(int)(sigmoidf(v.x) * tm1);
        s.y = (unsigned char)(int)(sigmoidf(v.y) * tm1);
        s.z = (unsigned char)(int)(sigmoidf(v.z) * tm1);
        s.w = (unsigned char)(int)(sigmoidf(v.w) * tm1);
        *reinterpret_cast<uchar4*>(st + e) = s;
    } else {
        for (int i = e; i < n; ++i)
            st[i] = (unsigned char)(int)(sigmoidf(x[i]) * tm1);
    }
}

__global__ __launch_bounds__(256) void write_onehot_kernel(
    const unsigned char* __restrict__ st, float* __restrict__ out, int n) {
    const int t = blockIdx.y;
    const int e = (blockIdx.x * 256 + threadIdx.x) * 4;
    if (e + 3 < n) {
        uchar4 s = *reinterpret_cast<const uchar4*>(st + e);
        f32x4 o;
        o.x = (s.x == t) ? 1.0f : 0.0f;
        o.y = (s.y == t) ? 1.0f : 0.0f;
        o.z = (s.z == t) ? 1.0f : 0.0f;
        o.w = (s.w == t) ? 1.0f : 0.0f;
        *reinterpret_cast<f32x4*>(out + (size_t)t * n + e) = o;
    } else {
        for (int i = e; i < n; ++i)
            out[(size_t)t * n + i] = (st[i] == t) ? 1.0f : 0.0f;
    }
}

// Fallback if d_ws is too small: fused (recompute sigmoid per t-plane).
__global__ __launch_bounds__(256) void fused_onehot_kernel(
    const float* __restrict__ x, float* __restrict__ out, int n, float tm1) {
    const int t = blockIdx.y;
    const int e = (blockIdx.x * 256 + threadIdx.x) * 4;
    if (e + 3 < n) {
        f32x4 v = *reinterpret_cast<const f32x4*>(x + e);
        f32x4 o;
        o.x = ((int)(sigmoidf(v.x) * tm1) == t) ? 1.0f : 0.0f;
        o.y = ((int)(sigmoidf(v.y) * tm1) == t) ? 1.0f : 0.0f;
        o.z = ((int)(sigmoidf(v.z) * tm1) == t) ? 1.0f : 0.0f;
        o.w = ((int)(sigmoidf(v.w) * tm1) == t) ? 1.0f : 0.0f;
        *reinterpret_cast<f32x4*>(out + (size_t)t * n + e) = o;
    } else {
        for (int i = e; i < n; ++i)
            out[(size_t)t * n + i] = ((int)(sigmoidf(x[i]) * tm1) == t) ? 1.0f : 0.0f;
    }
}

extern "C" void kernel_launch(void* const* d_in, const int* in_sizes, int n_in,
                              void* d_out, int out_size, void* d_ws, size_t ws_size,
                              hipStream_t stream) {
    const float* x = (const float*)d_in[0];
    float* out = (float*)d_out;
    const int n = in_sizes[0];        // B*D = 1048576
    const int T = out_size / n;       // 100
    const float tm1 = (float)(T - 1);

    const int n4 = (n + 3) / 4;
    const int blocks_x = (n4 + 255) / 256;   // 1024

    if (ws_size >= (size_t)n) {
        unsigned char* st = (unsigned char*)d_ws;
        spike_time_kernel<<<blocks_x, 256, 0, stream>>>(x, st, n, tm1);
        dim3 grid(blocks_x, T);
        write_onehot_kernel<<<grid, 256, 0, stream>>>(st, out, n);
    } else {
        dim3 grid(blocks_x, T);
        fused_onehot_kernel<<<grid, 256, 0, stream>>>(x, out, n, tm1);
    }
}